// Round 1
// baseline (135.877 us; speedup 1.0000x reference)
//
#include <hip/hip_runtime.h>

// Problem: B=16384, X_DIM=1024, K=64, fp32.
// out[b] = 0.5 * ( sum_k (x_b . V[:,k])^2  -  sum_i x_bi^2 * w_i ),  w_i = sum_k V[i][k]^2
constexpr int XD = 1024;
constexpr int KD = 64;
constexpr int ROWS_PER_BLOCK = 64;   // lane <-> row
constexpr int WAVES = 8;             // 512 threads/block
constexpr int I_PER_WAVE = XD / WAVES;  // 128

// ---- kernel 0: w_i = sum_k V[i][k]^2  (tiny: 256 KiB read, 4 KiB write) ----
__global__ void wsq_kernel(const float* __restrict__ v, float* __restrict__ w) {
    int i = blockIdx.x * blockDim.x + threadIdx.x;
    if (i < XD) {
        const float4* vp = (const float4*)(v + (size_t)i * KD);
        float s = 0.f;
#pragma unroll
        for (int q = 0; q < KD / 4; ++q) {
            float4 t = vp[q];
            s = fmaf(t.x, t.x, s);
            s = fmaf(t.y, t.y, s);
            s = fmaf(t.z, t.z, s);
            s = fmaf(t.w, t.w, s);
        }
        w[i] = s;
    }
}

// ---- main kernel: y = x@V per row in VGPRs, V broadcast via SGPR s_loads ----
__global__ __launch_bounds__(512, 2)
void cross_main(const float* __restrict__ x, const float* __restrict__ v,
                const float* __restrict__ wsq, float* __restrict__ out) {
    // LDS tree-reduction buffers: 4 slots x 64 k x 64 lanes = 64 KiB (+1 KiB z)
    __shared__ float lds_y[4 * KD * 64];
    __shared__ float lds_z[4 * 64];

    const int tid  = threadIdx.x;
    const int lane = tid & 63;
    // Force wave index into an SGPR so V addressing is provably wave-uniform
    // -> compiler emits s_load_dwordx16 for V (scalar broadcast operand).
    const int wav  = __builtin_amdgcn_readfirstlane(tid >> 6);   // 0..7
    const int row  = blockIdx.x * ROWS_PER_BLOCK + lane;
    const int i0   = wav * I_PER_WAVE;

    float y[KD];
#pragma unroll
    for (int k = 0; k < KD; ++k) y[k] = 0.f;
    float z = 0.f;

    const float* xrow = x + (size_t)row * XD + i0;
    const float* vp   = v + (size_t)i0 * KD;
    const float* wp   = wsq + i0;

    for (int ii = 0; ii < I_PER_WAVE; ii += 4) {
        float4 x4 = *(const float4*)(xrow + ii);
        float xs0 = x4.x, xs1 = x4.y, xs2 = x4.z, xs3 = x4.w;
#pragma unroll
        for (int j = 0; j < 4; ++j) {
            float xv = (j == 0) ? xs0 : (j == 1) ? xs1 : (j == 2) ? xs2 : xs3;
            const float* vrow = vp + (size_t)(ii + j) * KD;   // wave-uniform address
#pragma unroll
            for (int k = 0; k < KD; ++k)
                y[k] = fmaf(xv, vrow[k], y[k]);               // v_fmac_f32 vgpr, vgpr, sgpr
            z = fmaf(xv * xv, wp[ii + j], z);
        }
    }

    // ---- cross-wave reduction: sum y (and z) over the 8 waves, THEN square ----
    // round 1: waves 4..7 -> slots 0..3
    if (wav >= 4) {
        int s = wav - 4;
#pragma unroll
        for (int k = 0; k < KD; ++k) lds_y[(s * KD + k) * 64 + lane] = y[k];
        lds_z[s * 64 + lane] = z;
    }
    __syncthreads();
    if (wav < 4) {
        int s = wav;
#pragma unroll
        for (int k = 0; k < KD; ++k) y[k] += lds_y[(s * KD + k) * 64 + lane];
        z += lds_z[s * 64 + lane];
    }
    __syncthreads();
    // round 2: waves 2,3 -> slots 0,1
    if (wav == 2 || wav == 3) {
        int s = wav - 2;
#pragma unroll
        for (int k = 0; k < KD; ++k) lds_y[(s * KD + k) * 64 + lane] = y[k];
        lds_z[s * 64 + lane] = z;
    }
    __syncthreads();
    if (wav < 2) {
        int s = wav;
#pragma unroll
        for (int k = 0; k < KD; ++k) y[k] += lds_y[(s * KD + k) * 64 + lane];
        z += lds_z[s * 64 + lane];
    }
    __syncthreads();
    // round 3: wave 1 -> slot 0
    if (wav == 1) {
#pragma unroll
        for (int k = 0; k < KD; ++k) lds_y[k * 64 + lane] = y[k];
        lds_z[lane] = z;
    }
    __syncthreads();
    if (wav == 0) {
#pragma unroll
        for (int k = 0; k < KD; ++k) y[k] += lds_y[k * 64 + lane];
        z += lds_z[lane];
        float s2 = 0.f;
#pragma unroll
        for (int k = 0; k < KD; ++k) s2 = fmaf(y[k], y[k], s2);
        out[row] = 0.5f * (s2 - z);
    }
}

extern "C" void kernel_launch(void* const* d_in, const int* in_sizes, int n_in,
                              void* d_out, int out_size, void* d_ws, size_t ws_size,
                              hipStream_t stream) {
    const float* x = (const float*)d_in[0];      // (B, 1024) fp32
    const float* v = (const float*)d_in[1];      // (1024, 64) fp32
    float* out = (float*)d_out;                  // (B, 1) fp32
    float* wsq = (float*)d_ws;                   // 1024 floats scratch

    const int B = in_sizes[0] / XD;              // 16384

    hipLaunchKernelGGL(wsq_kernel, dim3((XD + 255) / 256), dim3(256), 0, stream, v, wsq);
    hipLaunchKernelGGL(cross_main, dim3(B / ROWS_PER_BLOCK), dim3(512), 0, stream,
                       x, v, wsq, out);
}

// Round 2
// 121.041 us; speedup vs baseline: 1.1226x; 1.1226x over previous
//
#include <hip/hip_runtime.h>

// Problem: B=16384, X_DIM=1024, K=64, fp32 in/out.
// out[b] = 0.5 * ( sum_k (x_b . V[:,k])^2  -  sum_i x_bi^2 * w_i ),  w_i = sum_k V[i][k]^2
//
// Strategy: y = x@V via bf16 MFMA with hi/lo error compensation:
//   x = xh + xl, V = vh + vl (bf16 splits); y ~= xh@vh + xh@vl + xl@vh  (fp32 acc)
// Memory-bound on streaming x (64 MiB). V pre-swizzled into MFMA B-fragment
// order in workspace so main-loop B loads are coalesced dwordx4 from L2.

typedef short short8 __attribute__((ext_vector_type(8)));   // 8 bf16 = 4 VGPRs
typedef float f32x4 __attribute__((ext_vector_type(4)));

constexpr int XD = 1024;
constexpr int KD = 64;

static __device__ __forceinline__ unsigned short f2bf(float f) {
    union { float f; unsigned u; } v; v.f = f;
    unsigned r = v.u + 0x7FFFu + ((v.u >> 16) & 1u);   // RNE
    return (unsigned short)(r >> 16);
}
static __device__ __forceinline__ float bf2f(unsigned short h) {
    union { unsigned u; float f; } v; v.u = ((unsigned)h) << 16;
    return v.f;
}

// ---- prep: split V into bf16 hi/lo, swizzled to B-fragment order; build w ----
// B-fragment layout assumed for mfma_f32_16x16x32_bf16:
//   lane l holds B[k = (l>>4)*8 + j][n = l&15], j = 0..7
// ws layout (bytes):
//   bh  @ 0       : [it:32][t:4][lane:64][j:8] bf16   (131072 B)
//   bl  @ 131072  : same                               (131072 B)
//   wf  @ 262144  : [it:32][lane:64][j:8] fp32         ( 65536 B)
__global__ void prep_kernel(const float* __restrict__ v,
                            unsigned short* __restrict__ bh,
                            unsigned short* __restrict__ bl,
                            float* __restrict__ wf) {
    int idx = blockIdx.x * 256 + threadIdx.x;   // 0..8191
    int it = idx >> 8;        // i-tile 0..31 (32 i's each)
    int r  = idx & 255;
    int t  = r >> 6;          // col tile 0..3
    int l  = r & 63;          // lane
    int q  = l >> 4, m = l & 15;
    int base_i = it * 32 + q * 8;
    int n = t * 16 + m;
    size_t fo = ((size_t)(it * 4 + t) * 64 + l) * 8;
#pragma unroll
    for (int j = 0; j < 8; ++j) {
        float val = v[(size_t)(base_i + j) * KD + n];
        unsigned short h = f2bf(val);
        bh[fo + j] = h;
        bl[fo + j] = f2bf(val - bf2f(h));
    }
    if (t == 0) {   // w_i replicated over the 16 m-lanes (tiny, keeps main loads simple)
        size_t wo = ((size_t)it * 64 + l) * 8;
#pragma unroll
        for (int j = 0; j < 8; ++j) {
            const f32x4* vp = (const f32x4*)(v + (size_t)(base_i + j) * KD);
            float s = 0.f;
#pragma unroll
            for (int qq = 0; qq < KD / 4; ++qq) {
                f32x4 tv = vp[qq];
                s = fmaf(tv.x, tv.x, s); s = fmaf(tv.y, tv.y, s);
                s = fmaf(tv.z, tv.z, s); s = fmaf(tv.w, tv.w, s);
            }
            wf[wo + j] = s;
        }
    }
}

// ---- main: 256 thr = 4 waves; wave = 16-row strip x half the i-range ----
__global__ __launch_bounds__(256, 2)
void cross_mfma(const float* __restrict__ x,
                const unsigned short* __restrict__ bh,
                const unsigned short* __restrict__ bl,
                const float* __restrict__ wf,
                float* __restrict__ out) {
    __shared__ float lds_acc[2][64][17];   // pair-combine, pad 17 = conflict-free
    __shared__ float lds_z[2][16];
    __shared__ float lds_z2[2][16];

    const int tid = threadIdx.x;
    const int l = tid & 63;
    const int wav = tid >> 6;
    const int strip = wav >> 1;     // 0..1: which 16-row strip
    const int half = wav & 1;       // 0..1: which i-half
    const int q = l >> 4, m = l & 15;
    const int row0 = blockIdx.x * 32 + strip * 16;

    f32x4 c[4];
#pragma unroll
    for (int t = 0; t < 4; ++t) c[t] = f32x4{0.f, 0.f, 0.f, 0.f};
    float z = 0.f;

    // A-load base: lane reads x[row0+m][i0 + q*8 .. +7] (32 B contiguous;
    // lanes m,m+16,m+32,m+48 together cover 128 contiguous B -> coalesced)
    const float* xrow = x + (size_t)(row0 + m) * XD + q * 8;
    const short8* bhp = (const short8*)bh;
    const short8* blp = (const short8*)bl;

#pragma unroll 2
    for (int it = half * 16; it < half * 16 + 16; ++it) {
        const int i0 = it * 32;
        f32x4 xa = *(const f32x4*)(xrow + i0);
        f32x4 xb = *(const f32x4*)(xrow + i0 + 4);
        const f32x4* wp = (const f32x4*)(wf + ((size_t)it * 64 + l) * 8);
        f32x4 wa = wp[0], wb = wp[1];

        // z += x^2 * w  (fp32, exact path)
        z = fmaf(xa.x * xa.x, wa.x, z); z = fmaf(xa.y * xa.y, wa.y, z);
        z = fmaf(xa.z * xa.z, wa.z, z); z = fmaf(xa.w * xa.w, wa.w, z);
        z = fmaf(xb.x * xb.x, wb.x, z); z = fmaf(xb.y * xb.y, wb.y, z);
        z = fmaf(xb.z * xb.z, wb.z, z); z = fmaf(xb.w * xb.w, wb.w, z);

        // A fragments: hi/lo split in-register
        short8 ah, al_;
        float xs[8] = {xa.x, xa.y, xa.z, xa.w, xb.x, xb.y, xb.z, xb.w};
#pragma unroll
        for (int j = 0; j < 8; ++j) {
            unsigned short h = f2bf(xs[j]);
            ah[j] = (short)h;
            al_[j] = (short)f2bf(xs[j] - bf2f(h));
        }

        const size_t fbase = (size_t)(it * 4) * 64 + l;
#pragma unroll
        for (int t = 0; t < 4; ++t) {
            short8 vh = bhp[fbase + (size_t)t * 64];
            short8 vl = blp[fbase + (size_t)t * 64];
            c[t] = __builtin_amdgcn_mfma_f32_16x16x32_bf16(ah, vh, c[t], 0, 0, 0);
            c[t] = __builtin_amdgcn_mfma_f32_16x16x32_bf16(ah, vl, c[t], 0, 0, 0);
            c[t] = __builtin_amdgcn_mfma_f32_16x16x32_bf16(al_, vh, c[t], 0, 0, 0);
        }
    }

    // z: lane holds partial for row m (its q-chunk, its i-half) -> sum over q
    z += __shfl_xor(z, 16);
    z += __shfl_xor(z, 32);

    // pair-combine (sum partials over the two i-halves BEFORE squaring)
    if (half == 1) {
#pragma unroll
        for (int t = 0; t < 4; ++t)
#pragma unroll
            for (int r = 0; r < 4; ++r) lds_acc[strip][l][t * 4 + r] = c[t][r];
        if (l < 16) lds_z[strip][l] = z;
    }
    __syncthreads();

    float p[4] = {0.f, 0.f, 0.f, 0.f};
    if (half == 0) {
#pragma unroll
        for (int t = 0; t < 4; ++t)
#pragma unroll
            for (int r = 0; r < 4; ++r) c[t][r] += lds_acc[strip][l][t * 4 + r];
        z += lds_z[strip][m];
        if (l < 16) lds_z2[strip][l] = z;   // lanes 0..15 hold rows m=0..15

        // C layout: col = l&15, row = q*4 + reg. p[reg] = sum_n y[row][n]^2 partial
#pragma unroll
        for (int r = 0; r < 4; ++r)
#pragma unroll
            for (int t = 0; t < 4; ++t) p[r] = fmaf(c[t][r], c[t][r], p[r]);
        // reduce across the 16 lanes of the quad-group (masks < 16 stay in-group)
#pragma unroll
        for (int mask = 1; mask < 16; mask <<= 1)
#pragma unroll
            for (int r = 0; r < 4; ++r) p[r] += __shfl_xor(p[r], mask);
    }
    __syncthreads();

    if (half == 0 && m < 4) {
        const int reg = m;
        const int rl = q * 4 + reg;          // local row 0..15
        out[row0 + rl] = 0.5f * (p[reg] - lds_z2[strip][rl]);
    }
}

extern "C" void kernel_launch(void* const* d_in, const int* in_sizes, int n_in,
                              void* d_out, int out_size, void* d_ws, size_t ws_size,
                              hipStream_t stream) {
    const float* x = (const float*)d_in[0];      // (16384, 1024) fp32
    const float* v = (const float*)d_in[1];      // (1024, 64) fp32
    float* out = (float*)d_out;                  // (16384, 1) fp32

    unsigned short* bh = (unsigned short*)d_ws;                    // 131072 B
    unsigned short* bl = (unsigned short*)((char*)d_ws + 131072);  // 131072 B
    float* wf = (float*)((char*)d_ws + 262144);                    //  65536 B

    const int B = in_sizes[0] / XD;              // 16384

    hipLaunchKernelGGL(prep_kernel, dim3(32), dim3(256), 0, stream, v, bh, bl, wf);
    hipLaunchKernelGGL(cross_mfma, dim3(B / 32), dim3(256), 0, stream,
                       x, bh, bl, wf, out);
}

// Round 3
// 111.221 us; speedup vs baseline: 1.2217x; 1.0883x over previous
//
#include <hip/hip_runtime.h>

// Problem: B=16384, X_DIM=1024, K=64, fp32 in/out.
// out[b] = 0.5 * ( sum_k (x_b . V[:,k])^2  -  sum_i x_bi^2 * w_i ),  w_i = sum_k V[i][k]^2
//
// y = x@V via bf16 MFMA with hi/lo error compensation (3 products, fp32 acc).
// R3: 1024 blocks (16 rows each) x 4 waves (i-quarters) = 16 waves/CU;
//     3 independent accumulator sets -> 12 independent MFMA chains/wave.

typedef short short8 __attribute__((ext_vector_type(8)));   // 8 bf16 = 4 VGPRs
typedef float f32x4 __attribute__((ext_vector_type(4)));

constexpr int XD = 1024;
constexpr int KD = 64;

static __device__ __forceinline__ unsigned short f2bf(float f) {
    union { float f; unsigned u; } v; v.f = f;
    unsigned r = v.u + 0x7FFFu + ((v.u >> 16) & 1u);   // RNE
    return (unsigned short)(r >> 16);
}
static __device__ __forceinline__ float bf2f(unsigned short h) {
    union { unsigned u; float f; } v; v.u = ((unsigned)h) << 16;
    return v.f;
}

// ---- prep: split V into bf16 hi/lo, swizzled to B-fragment order; build w ----
// B-fragment layout (mfma_f32_16x16x32_bf16): lane l holds B[k=(l>>4)*8+j][n=l&15]
// ws layout (bytes):
//   bh @ 0      : [it:32][t:4][lane:64][j:8] bf16   (131072 B)
//   bl @ 131072 : same                               (131072 B)
//   wf @ 262144 : [it:32][lane:64][j:8] fp32         ( 65536 B)
__global__ void prep_kernel(const float* __restrict__ v,
                            unsigned short* __restrict__ bh,
                            unsigned short* __restrict__ bl,
                            float* __restrict__ wf) {
    int idx = blockIdx.x * 256 + threadIdx.x;   // 0..8191
    int it = idx >> 8;
    int r  = idx & 255;
    int t  = r >> 6;
    int l  = r & 63;
    int q  = l >> 4, m = l & 15;
    int base_i = it * 32 + q * 8;
    int n = t * 16 + m;
    size_t fo = ((size_t)(it * 4 + t) * 64 + l) * 8;
#pragma unroll
    for (int j = 0; j < 8; ++j) {
        float val = v[(size_t)(base_i + j) * KD + n];
        unsigned short h = f2bf(val);
        bh[fo + j] = h;
        bl[fo + j] = f2bf(val - bf2f(h));
    }
    if (t == 0) {
        size_t wo = ((size_t)it * 64 + l) * 8;
#pragma unroll
        for (int j = 0; j < 8; ++j) {
            const f32x4* vp = (const f32x4*)(v + (size_t)(base_i + j) * KD);
            float s = 0.f;
#pragma unroll
            for (int qq = 0; qq < KD / 4; ++qq) {
                f32x4 tv = vp[qq];
                s = fmaf(tv.x, tv.x, s); s = fmaf(tv.y, tv.y, s);
                s = fmaf(tv.z, tv.z, s); s = fmaf(tv.w, tv.w, s);
            }
            wf[wo + j] = s;
        }
    }
}

// ---- main: block = 16 rows; 4 waves = 4 i-quarters (8 i-tiles each) ----
__global__ __launch_bounds__(256, 4)
void cross_mfma(const float* __restrict__ x,
                const unsigned short* __restrict__ bh,
                const unsigned short* __restrict__ bl,
                const float* __restrict__ wf,
                float* __restrict__ out) {
    __shared__ float lds_acc[3][64][17];   // pad 17 -> conflict-free
    __shared__ float lds_z[3][16];

    const int tid = threadIdx.x;
    const int l = tid & 63;
    const int wav = tid >> 6;           // 0..3 = i-quarter
    const int q = l >> 4, m = l & 15;
    const int row0 = blockIdx.x * 16;

    // 3 independent accumulator sets -> 12 independent MFMA chains
    f32x4 ch[4], cl1[4], cl2[4];
#pragma unroll
    for (int t = 0; t < 4; ++t) {
        ch[t] = f32x4{0.f, 0.f, 0.f, 0.f};
        cl1[t] = f32x4{0.f, 0.f, 0.f, 0.f};
        cl2[t] = f32x4{0.f, 0.f, 0.f, 0.f};
    }
    float z = 0.f;

    const float* xrow = x + (size_t)(row0 + m) * XD + q * 8;
    const short8* bhp = (const short8*)bh;
    const short8* blp = (const short8*)bl;

#pragma unroll 2
    for (int it = wav * 8; it < wav * 8 + 8; ++it) {
        const int i0 = it * 32;
        f32x4 xa = *(const f32x4*)(xrow + i0);
        f32x4 xb = *(const f32x4*)(xrow + i0 + 4);
        const f32x4* wp = (const f32x4*)(wf + ((size_t)it * 64 + l) * 8);
        f32x4 wa = wp[0], wb = wp[1];

        // z += x^2 * w  (exact fp32 path)
        z = fmaf(xa.x * xa.x, wa.x, z); z = fmaf(xa.y * xa.y, wa.y, z);
        z = fmaf(xa.z * xa.z, wa.z, z); z = fmaf(xa.w * xa.w, wa.w, z);
        z = fmaf(xb.x * xb.x, wb.x, z); z = fmaf(xb.y * xb.y, wb.y, z);
        z = fmaf(xb.z * xb.z, wb.z, z); z = fmaf(xb.w * xb.w, wb.w, z);

        // A fragments: hi/lo split in-register
        short8 ah, al_;
        float xs[8] = {xa.x, xa.y, xa.z, xa.w, xb.x, xb.y, xb.z, xb.w};
#pragma unroll
        for (int j = 0; j < 8; ++j) {
            unsigned short h = f2bf(xs[j]);
            ah[j] = (short)h;
            al_[j] = (short)f2bf(xs[j] - bf2f(h));
        }

        const size_t fbase = (size_t)(it * 4) * 64 + l;
#pragma unroll
        for (int t = 0; t < 4; ++t) {
            short8 vh = bhp[fbase + (size_t)t * 64];
            short8 vl = blp[fbase + (size_t)t * 64];
            ch[t]  = __builtin_amdgcn_mfma_f32_16x16x32_bf16(ah,  vh, ch[t],  0, 0, 0);
            cl1[t] = __builtin_amdgcn_mfma_f32_16x16x32_bf16(ah,  vl, cl1[t], 0, 0, 0);
            cl2[t] = __builtin_amdgcn_mfma_f32_16x16x32_bf16(al_, vh, cl2[t], 0, 0, 0);
        }
    }

    // merge the 3 products (exact fp32 adds)
    f32x4 cs[4];
#pragma unroll
    for (int t = 0; t < 4; ++t) cs[t] = ch[t] + cl1[t] + cl2[t];

    // z: sum over q-chunks -> every lane holds full-q z for its row m (this i-quarter)
    z += __shfl_xor(z, 16);
    z += __shfl_xor(z, 32);

    // 4-way combine across waves (sum partial y BEFORE squaring)
    if (wav > 0) {
        const int s = wav - 1;
#pragma unroll
        for (int t = 0; t < 4; ++t)
#pragma unroll
            for (int r = 0; r < 4; ++r) lds_acc[s][l][t * 4 + r] = cs[t][r];
        if (l < 16) lds_z[s][l] = z;
    }
    __syncthreads();

    if (wav == 0) {
#pragma unroll
        for (int s = 0; s < 3; ++s) {
#pragma unroll
            for (int t = 0; t < 4; ++t)
#pragma unroll
                for (int r = 0; r < 4; ++r) cs[t][r] += lds_acc[s][l][t * 4 + r];
            z += lds_z[s][m];
        }

        // C layout: col = l&15, row = q*4 + reg. p[reg] = sum over all 64 cols of y^2
        float p[4] = {0.f, 0.f, 0.f, 0.f};
#pragma unroll
        for (int r = 0; r < 4; ++r)
#pragma unroll
            for (int t = 0; t < 4; ++t) p[r] = fmaf(cs[t][r], cs[t][r], p[r]);
#pragma unroll
        for (int mask = 1; mask < 16; mask <<= 1)
#pragma unroll
            for (int r = 0; r < 4; ++r) p[r] += __shfl_xor(p[r], mask);

        // z for row (q*4 + m) lives in the lane whose m-part equals q*4+m
        float zrow = __shfl(z, q * 4 + m, 16);
        if (m < 4) out[row0 + q * 4 + m] = 0.5f * (p[m] - zrow);
    }
}

extern "C" void kernel_launch(void* const* d_in, const int* in_sizes, int n_in,
                              void* d_out, int out_size, void* d_ws, size_t ws_size,
                              hipStream_t stream) {
    const float* x = (const float*)d_in[0];      // (16384, 1024) fp32
    const float* v = (const float*)d_in[1];      // (1024, 64) fp32
    float* out = (float*)d_out;                  // (16384, 1) fp32

    unsigned short* bh = (unsigned short*)d_ws;                    // 131072 B
    unsigned short* bl = (unsigned short*)((char*)d_ws + 131072);  // 131072 B
    float* wf = (float*)((char*)d_ws + 262144);                    //  65536 B

    const int B = in_sizes[0] / XD;              // 16384

    hipLaunchKernelGGL(prep_kernel, dim3(32), dim3(256), 0, stream, v, bh, bl, wf);
    hipLaunchKernelGGL(cross_mfma, dim3(B / 16), dim3(256), 0, stream,
                       x, bh, bl, wf, out);
}

// Round 4
// 106.415 us; speedup vs baseline: 1.2769x; 1.0452x over previous
//
#include <hip/hip_runtime.h>

// Problem: B=16384, X_DIM=1024, K=64, fp32 in/out.
// out[b] = 0.5 * ( sum_k (x_b . V[:,k])^2  -  sum_i x_bi^2 * w_i ),  w_i = sum_k V[i][k]^2
//
// R4: x reads were the bottleneck (4-KB power-of-2 stride -> ~700 GB/s effective).
// Now each block stages 16 FULL rows of x (64 KB contiguous global) into LDS with
// flat 1KB-per-instr loads, then computes MFMA A-fragments from LDS (pitch 1025
// -> 2-way banks = free). y = x@V via bf16 hi/lo MFMA (3 products, fp32 acc).

typedef short short8 __attribute__((ext_vector_type(8)));   // 8 bf16 = 4 VGPRs
typedef float f32x4 __attribute__((ext_vector_type(4)));

constexpr int XD = 1024;
constexpr int KD = 64;
constexpr int PITCH = 1025;   // LDS floats per row; +1 breaks power-of-2 bank aliasing

static __device__ __forceinline__ unsigned short f2bf(float f) {
    union { float f; unsigned u; } v; v.f = f;
    unsigned r = v.u + 0x7FFFu + ((v.u >> 16) & 1u);   // RNE
    return (unsigned short)(r >> 16);
}
static __device__ __forceinline__ float bf2f(unsigned short h) {
    union { unsigned u; float f; } v; v.u = ((unsigned)h) << 16;
    return v.f;
}

// ---- prep: split V into bf16 hi/lo, swizzled to B-fragment order; build w ----
// B-fragment layout (mfma_f32_16x16x32_bf16): lane l holds B[k=(l>>4)*8+j][n=l&15]
// ws layout (bytes):
//   bh @ 0      : [it:32][t:4][lane:64][j:8] bf16   (131072 B)
//   bl @ 131072 : same                               (131072 B)
//   wf @ 262144 : [it:32][lane:64][j:8] fp32         ( 65536 B)
__global__ void prep_kernel(const float* __restrict__ v,
                            unsigned short* __restrict__ bh,
                            unsigned short* __restrict__ bl,
                            float* __restrict__ wf) {
    int idx = blockIdx.x * 256 + threadIdx.x;   // 0..8191
    int it = idx >> 8;
    int r  = idx & 255;
    int t  = r >> 6;
    int l  = r & 63;
    int q  = l >> 4, m = l & 15;
    int base_i = it * 32 + q * 8;
    int n = t * 16 + m;
    size_t fo = ((size_t)(it * 4 + t) * 64 + l) * 8;
#pragma unroll
    for (int j = 0; j < 8; ++j) {
        float val = v[(size_t)(base_i + j) * KD + n];
        unsigned short h = f2bf(val);
        bh[fo + j] = h;
        bl[fo + j] = f2bf(val - bf2f(h));
    }
    if (t == 0) {
        size_t wo = ((size_t)it * 64 + l) * 8;
#pragma unroll
        for (int j = 0; j < 8; ++j) {
            const f32x4* vp = (const f32x4*)(v + (size_t)(base_i + j) * KD);
            float s = 0.f;
#pragma unroll
            for (int qq = 0; qq < KD / 4; ++qq) {
                f32x4 tv = vp[qq];
                s = fmaf(tv.x, tv.x, s); s = fmaf(tv.y, tv.y, s);
                s = fmaf(tv.z, tv.z, s); s = fmaf(tv.w, tv.w, s);
            }
            wf[wo + j] = s;
        }
    }
}

// ---- main: block = 16 FULL rows; 8 waves split the 32 i-tiles (4 each) ----
__global__ __launch_bounds__(512, 4)
void cross_flat(const float* __restrict__ x,
                const unsigned short* __restrict__ bh,
                const unsigned short* __restrict__ bl,
                const float* __restrict__ wf,
                float* __restrict__ out) {
    // xbuf: 16 rows x PITCH floats = 65,600 B.
    // After compute, the front of the same buffer is reused as the 7-slot
    // combine area: slot s, lane l, idx -> smem[s*1088 + l*17 + idx] (30,464 B).
    __shared__ float smem[16 * PITCH];
    __shared__ float zbuf[7][16];

    const int tid = threadIdx.x;
    const int l = tid & 63;
    const int w = tid >> 6;            // wave 0..7
    const int q = l >> 4, m = l & 15;
    const int row0 = blockIdx.x * 16;

    // ---- stage: wave w loads rows 2w, 2w+1 (each 4 KB contiguous global) ----
#pragma unroll
    for (int k = 0; k < 8; ++k) {
        const int r   = 2 * w + (k >> 2);
        const int off = (k & 3) * 256 + l * 4;          // float index within row
        f32x4 v4 = *(const f32x4*)(x + (size_t)(row0 + r) * XD + off);
        float* d = &smem[r * PITCH + off];
        d[0] = v4.x; d[1] = v4.y; d[2] = v4.z; d[3] = v4.w;
    }
    __syncthreads();

    // ---- compute: wave w handles i-tiles 4w .. 4w+3 ----
    f32x4 ch[4], cl1[4], cl2[4];
#pragma unroll
    for (int t = 0; t < 4; ++t) {
        ch[t]  = f32x4{0.f, 0.f, 0.f, 0.f};
        cl1[t] = f32x4{0.f, 0.f, 0.f, 0.f};
        cl2[t] = f32x4{0.f, 0.f, 0.f, 0.f};
    }
    float z = 0.f;

    const short8* bhp = (const short8*)bh;
    const short8* blp = (const short8*)bl;

#pragma unroll
    for (int ii = 0; ii < 4; ++ii) {
        const int it = w * 4 + ii;
        // A fragment from LDS: x[row0+m][it*32 + q*8 + j], banks = (m+8q+j)%32 -> 2-way
        const float* xr = &smem[m * PITCH + it * 32 + q * 8];
        float xs[8];
#pragma unroll
        for (int j = 0; j < 8; ++j) xs[j] = xr[j];

        const f32x4* wp = (const f32x4*)(wf + ((size_t)it * 64 + l) * 8);
        f32x4 wa = wp[0], wb = wp[1];
        z = fmaf(xs[0] * xs[0], wa.x, z); z = fmaf(xs[1] * xs[1], wa.y, z);
        z = fmaf(xs[2] * xs[2], wa.z, z); z = fmaf(xs[3] * xs[3], wa.w, z);
        z = fmaf(xs[4] * xs[4], wb.x, z); z = fmaf(xs[5] * xs[5], wb.y, z);
        z = fmaf(xs[6] * xs[6], wb.z, z); z = fmaf(xs[7] * xs[7], wb.w, z);

        short8 ah, al_;
#pragma unroll
        for (int j = 0; j < 8; ++j) {
            unsigned short h = f2bf(xs[j]);
            ah[j] = (short)h;
            al_[j] = (short)f2bf(xs[j] - bf2f(h));
        }

        const size_t fbase = (size_t)(it * 4) * 64 + l;
#pragma unroll
        for (int t = 0; t < 4; ++t) {
            short8 vh = bhp[fbase + (size_t)t * 64];
            short8 vl = blp[fbase + (size_t)t * 64];
            ch[t]  = __builtin_amdgcn_mfma_f32_16x16x32_bf16(ah,  vh, ch[t],  0, 0, 0);
            cl1[t] = __builtin_amdgcn_mfma_f32_16x16x32_bf16(ah,  vl, cl1[t], 0, 0, 0);
            cl2[t] = __builtin_amdgcn_mfma_f32_16x16x32_bf16(al_, vh, cl2[t], 0, 0, 0);
        }
    }

    f32x4 cs[4];
#pragma unroll
    for (int t = 0; t < 4; ++t) cs[t] = ch[t] + cl1[t] + cl2[t];

    // z: sum over q-chunks -> full-q partial z for row m (this wave's i-range)
    z += __shfl_xor(z, 16);
    z += __shfl_xor(z, 32);

    __syncthreads();   // all xbuf reads done; safe to reuse smem as combine area

    if (w > 0) {
        const int s = w - 1;
#pragma unroll
        for (int t = 0; t < 4; ++t)
#pragma unroll
            for (int r = 0; r < 4; ++r) smem[s * 1088 + l * 17 + t * 4 + r] = cs[t][r];
        if (l < 16) zbuf[s][l] = z;
    }
    __syncthreads();

    if (w == 0) {
#pragma unroll
        for (int s = 0; s < 7; ++s) {
#pragma unroll
            for (int t = 0; t < 4; ++t)
#pragma unroll
                for (int r = 0; r < 4; ++r) cs[t][r] += smem[s * 1088 + l * 17 + t * 4 + r];
            z += zbuf[s][m];
        }

        // C layout: col = l&15, row = q*4 + reg. p[reg] = sum over all 64 cols of y^2
        float p[4] = {0.f, 0.f, 0.f, 0.f};
#pragma unroll
        for (int r = 0; r < 4; ++r)
#pragma unroll
            for (int t = 0; t < 4; ++t) p[r] = fmaf(cs[t][r], cs[t][r], p[r]);
#pragma unroll
        for (int mask = 1; mask < 16; mask <<= 1)
#pragma unroll
            for (int r = 0; r < 4; ++r) p[r] += __shfl_xor(p[r], mask);

        // z for row (q*4 + m) lives in the lane whose m-part equals q*4+m
        float zrow = __shfl(z, q * 4 + m, 16);
        if (m < 4) out[row0 + q * 4 + m] = 0.5f * (p[m] - zrow);
    }
}

extern "C" void kernel_launch(void* const* d_in, const int* in_sizes, int n_in,
                              void* d_out, int out_size, void* d_ws, size_t ws_size,
                              hipStream_t stream) {
    const float* x = (const float*)d_in[0];      // (16384, 1024) fp32
    const float* v = (const float*)d_in[1];      // (1024, 64) fp32
    float* out = (float*)d_out;                  // (16384, 1) fp32

    unsigned short* bh = (unsigned short*)d_ws;                    // 131072 B
    unsigned short* bl = (unsigned short*)((char*)d_ws + 131072);  // 131072 B
    float* wf = (float*)((char*)d_ws + 262144);                    //  65536 B

    const int B = in_sizes[0] / XD;              // 16384

    hipLaunchKernelGGL(prep_kernel, dim3(32), dim3(256), 0, stream, v, bh, bl, wf);
    hipLaunchKernelGGL(cross_flat, dim3(B / 16), dim3(512), 0, stream,
                       x, bh, bl, wf, out);
}